// Round 4
// baseline (3944.809 us; speedup 1.0000x reference)
//
#include <hip/hip_runtime.h>
#include <stdint.h>

#define HW 256
#define HWP 258
#define CH 32
#define CVN 64
#define NPIX (HW*HW)
#define KK 8
#define CSTR (HWP*HWP)

// PRNG (verified round 3): partitionable threefry + SPLIT-key randint.
// This round: same math, 8x/6x/8x more thread-parallelism (latency-bound fix).

// ---------------- Threefry-2x32 (JAX-compatible) ----------------
__host__ __device__ __forceinline__ void tf2x32(uint32_t k0, uint32_t k1,
                                                uint32_t x0, uint32_t x1,
                                                uint32_t &o0, uint32_t &o1) {
  const uint32_t ks2 = k0 ^ k1 ^ 0x1BD11BDAu;
  x0 += k0; x1 += k1;
#define TFR(r) x0 += x1; x1 = (x1 << (r)) | (x1 >> (32 - (r))); x1 ^= x0;
  TFR(13) TFR(15) TFR(26) TFR(6)
  x0 += k1;  x1 += ks2 + 1u;
  TFR(17) TFR(29) TFR(16) TFR(24)
  x0 += ks2; x1 += k0 + 2u;
  TFR(13) TFR(15) TFR(26) TFR(6)
  x0 += k0;  x1 += k1 + 3u;
  TFR(17) TFR(29) TFR(16) TFR(24)
  x0 += k1;  x1 += ks2 + 4u;
  TFR(13) TFR(15) TFR(26) TFR(6)
  x0 += ks2; x1 += k0 + 5u;
#undef TFR
  o0 = x0; o1 = x1;
}

__device__ __forceinline__ uint32_t tfbits(uint32_t k0, uint32_t k1, uint32_t idx) {
  uint32_t a, b;
  tf2x32(k0, k1, 0u, idx, a, b);
  return a ^ b;
}

// ---------------- zero-pad q,k into (C, 258, 258) ----------------
__global__ void pad_k(const float* __restrict__ q, const float* __restrict__ k,
                      float* __restrict__ qp, float* __restrict__ kp) {
  int idx = blockIdx.x * blockDim.x + threadIdx.x;
  const int total = 2 * CH * CSTR;
  if (idx >= total) return;
  int xx = idx % HWP;
  int t = idx / HWP;
  int yy = t % HWP;
  int bc = t / HWP;  // b*CH + c
  float qv = 0.f, kv = 0.f;
  if (xx >= 1 && xx <= HW && yy >= 1 && yy <= HW) {
    int src = (bc * HW + (yy - 1)) * HW + (xx - 1);
    qv = q[src];
    kv = k[src];
  }
  qp[idx] = qv;
  kp[idx] = kv;
}

// ---------------- single-candidate patch cost, bit-exact order ----------------
// cost = sum_{dy}{ S0+S1+S2 }, each S = sequential sum over c of (q-k)^2
__device__ __forceinline__ float patch_cost1(const float* __restrict__ qp,
                                             const float* __restrict__ kp,
                                             int y, int x, int sy, int sx) {
#pragma clang fp contract(off)
  float cost = 0.f;
  for (int dy = 0; dy < 3; dy++) {
    float S0 = 0.f, S1 = 0.f, S2 = 0.f;
    const float* qr = qp + (y + dy) * HWP + x;
    const float* kr = kp + (sy + dy) * HWP + sx;
    for (int c = 0; c < CH; c++) {
      float d0 = qr[0] - kr[0]; float t0 = d0 * d0;
      float d1 = qr[1] - kr[1]; float t1 = d1 * d1;
      float d2 = qr[2] - kr[2]; float t2 = d2 * d2;
      S0 = S0 + t0;
      S1 = S1 + t1;
      S2 = S2 + t2;
      qr += CSTR; kr += CSTR;
    }
    cost = cost + S0;
    cost = cost + S1;
    cost = cost + S2;
  }
  return cost;
}

// ---------------- init: 32 px x 8 cand per block ----------------
__global__ void init2_k(const float* __restrict__ qp, const float* __restrict__ kp,
                        float* __restrict__ cO, int* __restrict__ sO,
                        uint32_t kA0, uint32_t kA1, uint32_t kB0, uint32_t kB1) {
  __shared__ float lc[32][KK + 1];
  __shared__ int ls[32][KK + 1];
  int j = threadIdx.x >> 5;      // candidate 0..7
  int pl = threadIdx.x & 31;     // pixel-in-block
  int gpix = blockIdx.x * 32 + pl;
  int b = gpix >> 16, p = gpix & 0xFFFF;
  int y = p >> 8, x = p & 255;
  uint32_t k0 = b ? kB0 : kA0, k1 = b ? kB1 : kA1;
  // fold_in(key, 10000/10001); randint span=256 -> mult 0 -> only lower bits
  // (key = k2 = enc(fold,(0,1)))
  uint32_t f0, f1, ky0, ky1, kx0, kx1;
  tf2x32(k0, k1, 0u, 10000u, f0, f1);
  tf2x32(f0, f1, 0u, 1u, ky0, ky1);
  tf2x32(k0, k1, 0u, 10001u, f0, f1);
  tf2x32(f0, f1, 0u, 1u, kx0, kx1);
  uint32_t cand = (uint32_t)(j * NPIX + p);
  int sy = (int)(tfbits(ky0, ky1, cand) & 255u);
  int sx = (int)(tfbits(kx0, kx1, cand) & 255u);
  const float* qpb = qp + (size_t)b * CH * CSTR;
  const float* kpb = kp + (size_t)b * CH * CSTR;
  float c = patch_cost1(qpb, kpb, y, x, sy, sx);
  lc[pl][j] = c;
  ls[pl][j] = (sy << 8) | sx;
  __syncthreads();
  if (threadIdx.x < 32) {
    float c8[KK];
    int s8[KK];
#pragma unroll
    for (int jj = 0; jj < KK; jj++) { c8[jj] = lc[pl][jj]; s8[jj] = ls[pl][jj]; }
    // stable odd-even transposition sort (== lax.top_k tie semantics)
#pragma unroll
    for (int ph = 0; ph < KK; ph++) {
#pragma unroll
      for (int i = (ph & 1); i + 1 < KK; i += 2) {
        if (c8[i] > c8[i + 1]) {
          float tc = c8[i]; c8[i] = c8[i + 1]; c8[i + 1] = tc;
          int ts = s8[i]; s8[i] = s8[i + 1]; s8[i + 1] = ts;
        }
      }
    }
    int base = b * KK * NPIX;
#pragma unroll
    for (int jj = 0; jj < KK; jj++) {
      cO[base + jj * NPIX + p] = c8[jj];
      sO[base + jj * NPIX + p] = s8[jj];
    }
  }
}

// ---------------- iter: 32 px x 6 cand per 192-thread block ----------------
__global__ void iter2_k(const float* __restrict__ qp, const float* __restrict__ kp,
                        const float* __restrict__ cI, const int* __restrict__ sI,
                        float* __restrict__ cO, int* __restrict__ sO,
                        int it, uint32_t kA0, uint32_t kA1, uint32_t kB0, uint32_t kB1) {
  __shared__ float lc[32][6];
  __shared__ int ls[32][6];
  int j = threadIdx.x >> 5;      // candidate 0..5
  int pl = threadIdx.x & 31;
  int gpix = blockIdx.x * 32 + pl;
  int b = gpix >> 16, p = gpix & 0xFFFF;
  int y = p >> 8, x = p & 255;
  int base = b * KK * NPIX;

  int nsy, nsx;
  if (j < 4) {
    // propagation candidates (jnp.roll wraps)
    int np;
    if (j == 0)      np = (y << 8) | ((x + HW - 1) & (HW - 1));
    else if (j == 1) np = (y << 8) | ((x + 1) & (HW - 1));
    else if (j == 2) np = (((y + HW - 1) & (HW - 1)) << 8) | x;
    else             np = (((y + 1) & (HW - 1)) << 8) | x;
    int sv = sI[base + np];
    if (j == 0)      { nsy = sv >> 8;       nsx = (sv & 255) + 1; }
    else if (j == 1) { nsy = sv >> 8;       nsx = (sv & 255) - 1; }
    else if (j == 2) { nsy = (sv >> 8) + 1; nsx = sv & 255; }
    else             { nsy = (sv >> 8) - 1; nsx = sv & 255; }
  } else {
    int svc = sI[base + p];
    int by = svc >> 8, bx = svc & 255;
    uint32_t k0 = b ? kB0 : kA0, k1 = b ? kB1 : kA1;
    uint32_t kit0, kit1, f0, f1;
    tf2x32(k0, k1, 0u, (uint32_t)it, kit0, kit1);  // kit = fold_in(key, it)
    uint32_t e = (uint32_t)p;
    if (j == 4) {
      // rad=128, span 257, mult=1: off = ((hi%257)+(lo%257)) % 257
      uint32_t h0, h1, l0, l1, hi, lo;
      tf2x32(kit0, kit1, 0u, 0u, f0, f1);   // fold_in(kit,0) -> dy
      tf2x32(f0, f1, 0u, 0u, h0, h1);
      tf2x32(f0, f1, 0u, 1u, l0, l1);
      hi = tfbits(h0, h1, e); lo = tfbits(l0, l1, e);
      nsy = by + (-128 + (int)(((hi % 257u) + (lo % 257u)) % 257u));
      tf2x32(kit0, kit1, 0u, 1u, f0, f1);   // fold_in(kit,1) -> dx
      tf2x32(f0, f1, 0u, 0u, h0, h1);
      tf2x32(f0, f1, 0u, 1u, l0, l1);
      hi = tfbits(h0, h1, e); lo = tfbits(l0, l1, e);
      nsx = bx + (-128 + (int)(((hi % 257u) + (lo % 257u)) % 257u));
    } else {
      // rad=64, span 129, mult=16: off = ((hi%129)*16+(lo%129)) % 129
      uint32_t h0, h1, l0, l1, hi, lo;
      tf2x32(kit0, kit1, 0u, 2u, f0, f1);   // fold_in(kit,2) -> dy
      tf2x32(f0, f1, 0u, 0u, h0, h1);
      tf2x32(f0, f1, 0u, 1u, l0, l1);
      hi = tfbits(h0, h1, e); lo = tfbits(l0, l1, e);
      nsy = by + (-64 + (int)((((hi % 129u) * 16u) + (lo % 129u)) % 129u));
      tf2x32(kit0, kit1, 0u, 3u, f0, f1);   // fold_in(kit,3) -> dx
      tf2x32(f0, f1, 0u, 0u, h0, h1);
      tf2x32(f0, f1, 0u, 1u, l0, l1);
      hi = tfbits(h0, h1, e); lo = tfbits(l0, l1, e);
      nsx = bx + (-64 + (int)((((hi % 129u) * 16u) + (lo % 129u)) % 129u));
    }
  }
  nsy = min(max(nsy, 0), HW - 1);
  nsx = min(max(nsx, 0), HW - 1);

  const float* qpb = qp + (size_t)b * CH * CSTR;
  const float* kpb = kp + (size_t)b * CH * CSTR;
  float c = patch_cost1(qpb, kpb, y, x, nsy, nsx);
  lc[pl][j] = c;
  ls[pl][j] = (nsy << 8) | nsx;
  __syncthreads();

  if (threadIdx.x < 32) {
    float c14[KK + 6];
    int s14[KK + 6];
#pragma unroll
    for (int jj = 0; jj < KK; jj++) {
      c14[jj] = cI[base + jj * NPIX + p];
      s14[jj] = sI[base + jj * NPIX + p];
    }
#pragma unroll
    for (int jj = 0; jj < 6; jj++) {
      c14[KK + jj] = lc[pl][jj];
      s14[KK + jj] = ls[pl][jj];
    }
    // stable odd-even transposition sort of 14
#pragma unroll
    for (int ph = 0; ph < 14; ph++) {
#pragma unroll
      for (int i = (ph & 1); i + 1 < 14; i += 2) {
        if (c14[i] > c14[i + 1]) {
          float tc = c14[i]; c14[i] = c14[i + 1]; c14[i + 1] = tc;
          int ts = s14[i]; s14[i] = s14[i + 1]; s14[i + 1] = ts;
        }
      }
    }
#pragma unroll
    for (int jj = 0; jj < KK; jj++) {
      cO[base + jj * NPIX + p] = c14[jj];
      sO[base + jj * NPIX + p] = s14[jj];
    }
  }
}

// ---------------- softmax attention gather: 32 px x 8 ch-groups ----------------
__global__ void attn2_k(const float* __restrict__ v, const float* __restrict__ cI,
                        const int* __restrict__ sI, float* __restrict__ out) {
  int g = threadIdx.x >> 5;      // channel group 0..7 (8 channels each)
  int pl = threadIdx.x & 31;
  int gpix = blockIdx.x * 32 + pl;
  int b = gpix >> 16, p = gpix & 0xFFFF;
  int base = b * KK * NPIX;
  float c[KK];
  int off[KK];
#pragma unroll
  for (int j = 0; j < KK; j++) {
    c[j] = cI[base + j * NPIX + p];
    off[j] = sI[base + j * NPIX + p];  // (sy<<8)|sx == sy*256+sx
  }
  float m = c[0];  // sorted ascending -> min cost
  float w[KK];
  float Z = 0.f;
#pragma unroll
  for (int j = 0; j < KK; j++) { w[j] = expf(m - c[j]); Z = Z + w[j]; }
#pragma unroll
  for (int j = 0; j < KK; j++) w[j] = w[j] / Z;
  const float* vb = v + (size_t)b * CVN * NPIX;
  float* ob = out + (size_t)b * CVN * NPIX;
#pragma unroll
  for (int i = 0; i < 8; i++) {
    int cv = g * 8 + i;
    const float* vc = vb + cv * NPIX;
    float acc = 0.f;
#pragma unroll
    for (int j = 0; j < KK; j++) acc = acc + w[j] * vc[off[j]];
    ob[cv * NPIX + p] = acc;
  }
}

extern "C" void kernel_launch(void* const* d_in, const int* in_sizes, int n_in,
                              void* d_out, int out_size, void* d_ws, size_t ws_size,
                              hipStream_t stream) {
  const float* q = (const float*)d_in[0];
  const float* k = (const float*)d_in[1];
  const float* v = (const float*)d_in[2];
  float* out = (float*)d_out;

  // base key: jax.random.key(42) -> (0,42); split -> enc(base,(0,i))
  uint32_t kA0, kA1, kB0, kB1;
  tf2x32(0u, 42u, 0u, 0u, kA0, kA1);
  tf2x32(0u, 42u, 0u, 1u, kB0, kB1);

  // workspace layout (floats): qpad | kpad | costA | costB | sA | sB
  float* qp = (float*)d_ws;
  float* kp = qp + (size_t)2 * CH * CSTR;
  float* cA = kp + (size_t)2 * CH * CSTR;
  float* cB = cA + (size_t)2 * KK * NPIX;
  int* sA = (int*)(cB + (size_t)2 * KK * NPIX);
  int* sB = sA + (size_t)2 * KK * NPIX;

  const int padTotal = 2 * CH * CSTR;
  pad_k<<<(padTotal + 255) / 256, 256, 0, stream>>>(q, k, qp, kp);

  const int nblk = (2 * NPIX) / 32;  // 4096
  init2_k<<<nblk, 256, 0, stream>>>(qp, kp, cA, sA, kA0, kA1, kB0, kB1);

  float* ci = cA; int* si = sA;
  float* co = cB; int* so = sB;
  for (int it = 0; it < 5; ++it) {
    iter2_k<<<nblk, 192, 0, stream>>>(qp, kp, ci, si, co, so, it,
                                      kA0, kA1, kB0, kB1);
    float* tc = ci; ci = co; co = tc;
    int* ts = si; si = so; so = ts;
  }
  attn2_k<<<nblk, 256, 0, stream>>>(v, ci, si, out);
}

// Round 5
// 1723.852 us; speedup vs baseline: 2.2884x; 2.2884x over previous
//
#include <hip/hip_runtime.h>
#include <stdint.h>

#define HW 256
#define HWP 258
#define CH 32
#define CVN 64
#define NPIX (HW*HW)
#define KK 8
#define CSTR (HWP*HWP)
#define NGRP 2048        // pixel-groups of 64 px (2 batches x 65536 / 64)
#define NBLK 1024        // co-resident blocks; each does 2 groups

// PRNG (verified r3): partitionable threefry + SPLIT-key randint.
// r4 post-mortem: >resident grid broke plane-lockstep -> 16x L2 overfetch.
// r5: co-resident 1024 blocks + grid-stride, c-outer loads, 2 cand/thread.

// ---------------- Threefry-2x32 (JAX-compatible) ----------------
__host__ __device__ __forceinline__ void tf2x32(uint32_t k0, uint32_t k1,
                                                uint32_t x0, uint32_t x1,
                                                uint32_t &o0, uint32_t &o1) {
  const uint32_t ks2 = k0 ^ k1 ^ 0x1BD11BDAu;
  x0 += k0; x1 += k1;
#define TFR(r) x0 += x1; x1 = (x1 << (r)) | (x1 >> (32 - (r))); x1 ^= x0;
  TFR(13) TFR(15) TFR(26) TFR(6)
  x0 += k1;  x1 += ks2 + 1u;
  TFR(17) TFR(29) TFR(16) TFR(24)
  x0 += ks2; x1 += k0 + 2u;
  TFR(13) TFR(15) TFR(26) TFR(6)
  x0 += k0;  x1 += k1 + 3u;
  TFR(17) TFR(29) TFR(16) TFR(24)
  x0 += k1;  x1 += ks2 + 4u;
  TFR(13) TFR(15) TFR(26) TFR(6)
  x0 += ks2; x1 += k0 + 5u;
#undef TFR
  o0 = x0; o1 = x1;
}

__device__ __forceinline__ uint32_t tfbits(uint32_t k0, uint32_t k1, uint32_t idx) {
  uint32_t a, b;
  tf2x32(k0, k1, 0u, idx, a, b);
  return a ^ b;
}

// ---------------- zero-pad q,k into (C, 258, 258) ----------------
__global__ void pad_k(const float* __restrict__ q, const float* __restrict__ k,
                      float* __restrict__ qp, float* __restrict__ kp) {
  int idx = blockIdx.x * blockDim.x + threadIdx.x;
  const int total = 2 * CH * CSTR;
  if (idx >= total) return;
  int xx = idx % HWP;
  int t = idx / HWP;
  int yy = t % HWP;
  int bc = t / HWP;  // b*CH + c
  float qv = 0.f, kv = 0.f;
  if (xx >= 1 && xx <= HW && yy >= 1 && yy <= HW) {
    int src = (bc * HW + (yy - 1)) * HW + (xx - 1);
    qv = q[src];
    kv = k[src];
  }
  qp[idx] = qv;
  kp[idx] = kv;
}

// ---------------- N-candidate patch cost, bit-exact, c-outer loads ----------
// 9 independent accumulators per candidate (each accumulates in c-order, same
// as reference); final reduction in the reference's flat (dy,dx) add order.
template<int NC>
__device__ __forceinline__ void patch_costN(const float* __restrict__ qp,
                                            const float* __restrict__ kp,
                                            int y, int x,
                                            const int* sy, const int* sx,
                                            float* cost) {
#pragma clang fp contract(off)
  float S[NC][3][3];
#pragma unroll
  for (int j = 0; j < NC; j++)
#pragma unroll
    for (int dy = 0; dy < 3; dy++)
#pragma unroll
      for (int dx = 0; dx < 3; dx++) S[j][dy][dx] = 0.f;
  const float* qb = qp + y * HWP + x;
  int kb[NC];
#pragma unroll
  for (int j = 0; j < NC; j++) kb[j] = sy[j] * HWP + sx[j];
  for (int c = 0; c < CH; c++) {
    const float* qc = qb + c * CSTR;
    float qv[3][3];
#pragma unroll
    for (int dy = 0; dy < 3; dy++)
#pragma unroll
      for (int dx = 0; dx < 3; dx++) qv[dy][dx] = qc[dy * HWP + dx];
    const float* kc = kp + c * CSTR;
#pragma unroll
    for (int j = 0; j < NC; j++) {
      const float* kr = kc + kb[j];
#pragma unroll
      for (int dy = 0; dy < 3; dy++) {
#pragma unroll
        for (int dx = 0; dx < 3; dx++) {
          float d = qv[dy][dx] - kr[dy * HWP + dx];
          S[j][dy][dx] = S[j][dy][dx] + d * d;
        }
      }
    }
  }
#pragma unroll
  for (int j = 0; j < NC; j++) {
    float cc = 0.f;
#pragma unroll
    for (int dy = 0; dy < 3; dy++)
#pragma unroll
      for (int dx = 0; dx < 3; dx++) cc = cc + S[j][dy][dx];
    cost[j] = cc;
  }
}

// ---------------- init: 64 px x 4 grp x 2 cand; grid-stride 2 ----------------
__global__ __launch_bounds__(256) void init3_k(
    const float* __restrict__ qp, const float* __restrict__ kp,
    float* __restrict__ cO, int* __restrict__ sO,
    uint32_t kA0, uint32_t kA1, uint32_t kB0, uint32_t kB1) {
  __shared__ float lc[64][KK + 1];
  __shared__ int ls[64][KK + 1];
  int g = threadIdx.x >> 6;      // 0..3
  int pl = threadIdx.x & 63;
  for (int pass = 0; pass < 2; ++pass) {
    int grp = blockIdx.x + pass * NBLK;
    int gpix = grp * 64 + pl;
    int b = gpix >> 16, p = gpix & 0xFFFF;
    int y = p >> 8, x = p & 255;
    uint32_t k0 = b ? kB0 : kA0, k1 = b ? kB1 : kA1;
    // fold_in(key,10000/10001); randint span=256 -> mult 0 -> lower bits only,
    // key = k2 = enc(fold,(0,1))
    uint32_t f0, f1, ky0, ky1, kx0, kx1;
    tf2x32(k0, k1, 0u, 10000u, f0, f1);
    tf2x32(f0, f1, 0u, 1u, ky0, ky1);
    tf2x32(k0, k1, 0u, 10001u, f0, f1);
    tf2x32(f0, f1, 0u, 1u, kx0, kx1);
    int sy[2], sx[2], jid[2];
    jid[0] = g; jid[1] = g + 4;
#pragma unroll
    for (int jj = 0; jj < 2; jj++) {
      uint32_t cand = (uint32_t)(jid[jj] * NPIX + p);
      sy[jj] = (int)(tfbits(ky0, ky1, cand) & 255u);
      sx[jj] = (int)(tfbits(kx0, kx1, cand) & 255u);
    }
    const float* qpb = qp + (size_t)b * CH * CSTR;
    const float* kpb = kp + (size_t)b * CH * CSTR;
    float c2[2];
    patch_costN<2>(qpb, kpb, y, x, sy, sx, c2);
#pragma unroll
    for (int jj = 0; jj < 2; jj++) {
      lc[pl][jid[jj]] = c2[jj];
      ls[pl][jid[jj]] = (sy[jj] << 8) | sx[jj];
    }
    __syncthreads();
    if (threadIdx.x < 64) {
      float c8[KK];
      int s8[KK];
#pragma unroll
      for (int jj = 0; jj < KK; jj++) { c8[jj] = lc[pl][jj]; s8[jj] = ls[pl][jj]; }
      // stable odd-even transposition sort (== lax.top_k tie semantics)
#pragma unroll
      for (int ph = 0; ph < KK; ph++) {
#pragma unroll
        for (int i = (ph & 1); i + 1 < KK; i += 2) {
          if (c8[i] > c8[i + 1]) {
            float tc = c8[i]; c8[i] = c8[i + 1]; c8[i + 1] = tc;
            int ts = s8[i]; s8[i] = s8[i + 1]; s8[i + 1] = ts;
          }
        }
      }
      int base = b * KK * NPIX;
#pragma unroll
      for (int jj = 0; jj < KK; jj++) {
        cO[base + jj * NPIX + p] = c8[jj];
        sO[base + jj * NPIX + p] = s8[jj];
      }
    }
    __syncthreads();
  }
}

// ---------------- prop/rand candidate helpers ----------------
__device__ __forceinline__ void prop_cand(const int* __restrict__ sI, int base,
                                          int y, int x, int c, int &nsy, int &nsx) {
  int np;
  if (c == 0)      np = (y << 8) | ((x + HW - 1) & (HW - 1));
  else if (c == 1) np = (y << 8) | ((x + 1) & (HW - 1));
  else if (c == 2) np = (((y + HW - 1) & (HW - 1)) << 8) | x;
  else             np = (((y + 1) & (HW - 1)) << 8) | x;
  int sv = sI[base + np];
  if (c == 0)      { nsy = sv >> 8;       nsx = (sv & 255) + 1; }
  else if (c == 1) { nsy = sv >> 8;       nsx = (sv & 255) - 1; }
  else if (c == 2) { nsy = (sv >> 8) + 1; nsx = sv & 255; }
  else             { nsy = (sv >> 8) - 1; nsx = sv & 255; }
}

// rand candidate: s = 0 (rad 128, span 257, mult 1) or 1 (rad 64, span 129, mult 16)
__device__ __forceinline__ void rand_cand(uint32_t kit0, uint32_t kit1, int s,
                                          uint32_t p, int by, int bx,
                                          int &nsy, int &nsx) {
  uint32_t f0, f1, h0, h1, l0, l1, hi, lo;
  // dy: fold_in(kit, 2s); dx: fold_in(kit, 2s+1); each randint splits its key
  tf2x32(kit0, kit1, 0u, (uint32_t)(2 * s), f0, f1);
  tf2x32(f0, f1, 0u, 0u, h0, h1);
  tf2x32(f0, f1, 0u, 1u, l0, l1);
  hi = tfbits(h0, h1, p); lo = tfbits(l0, l1, p);
  int offy = (s == 0) ? (int)(((hi % 257u) + (lo % 257u)) % 257u)
                      : (int)((((hi % 129u) * 16u) + (lo % 129u)) % 129u);
  tf2x32(kit0, kit1, 0u, (uint32_t)(2 * s + 1), f0, f1);
  tf2x32(f0, f1, 0u, 0u, h0, h1);
  tf2x32(f0, f1, 0u, 1u, l0, l1);
  hi = tfbits(h0, h1, p); lo = tfbits(l0, l1, p);
  int offx = (s == 0) ? (int)(((hi % 257u) + (lo % 257u)) % 257u)
                      : (int)((((hi % 129u) * 16u) + (lo % 129u)) % 129u);
  int rad = (s == 0) ? 128 : 64;
  nsy = by + (offy - rad);
  nsx = bx + (offx - rad);
}

// ---------------- iter: 64 px x 3 grp x 2 cand; grid-stride 2 ----------------
// grp g handles candidates {g, g+3}: g0:{p0,p3} g1:{p1,r4} g2:{p2,r5}
__global__ __launch_bounds__(192) void iter3_k(
    const float* __restrict__ qp, const float* __restrict__ kp,
    const float* __restrict__ cI, const int* __restrict__ sI,
    float* __restrict__ cO, int* __restrict__ sO,
    int it, uint32_t kA0, uint32_t kA1, uint32_t kB0, uint32_t kB1) {
  __shared__ float lc[64][7];
  __shared__ int ls[64][7];
  int g = threadIdx.x >> 6;      // 0..2
  int pl = threadIdx.x & 63;
  for (int pass = 0; pass < 2; ++pass) {
    int grp = blockIdx.x + pass * NBLK;
    int gpix = grp * 64 + pl;
    int b = gpix >> 16, p = gpix & 0xFFFF;
    int y = p >> 8, x = p & 255;
    int base = b * KK * NPIX;
    int nsy[2], nsx[2];
    prop_cand(sI, base, y, x, g, nsy[0], nsx[0]);
    if (g == 0) {
      prop_cand(sI, base, y, x, 3, nsy[1], nsx[1]);
    } else {
      int svc = sI[base + p];
      int by = svc >> 8, bx = svc & 255;
      uint32_t k0 = b ? kB0 : kA0, k1 = b ? kB1 : kA1;
      uint32_t kit0, kit1;
      tf2x32(k0, k1, 0u, (uint32_t)it, kit0, kit1);  // fold_in(key, it)
      rand_cand(kit0, kit1, g - 1, (uint32_t)p, by, bx, nsy[1], nsx[1]);
    }
#pragma unroll
    for (int jj = 0; jj < 2; jj++) {
      nsy[jj] = min(max(nsy[jj], 0), HW - 1);
      nsx[jj] = min(max(nsx[jj], 0), HW - 1);
    }
    const float* qpb = qp + (size_t)b * CH * CSTR;
    const float* kpb = kp + (size_t)b * CH * CSTR;
    float c2[2];
    patch_costN<2>(qpb, kpb, y, x, nsy, nsx, c2);
    lc[pl][g] = c2[0];     ls[pl][g] = (nsy[0] << 8) | nsx[0];
    lc[pl][g + 3] = c2[1]; ls[pl][g + 3] = (nsy[1] << 8) | nsx[1];
    __syncthreads();
    if (threadIdx.x < 64) {
      float c14[KK + 6];
      int s14[KK + 6];
#pragma unroll
      for (int jj = 0; jj < KK; jj++) {
        c14[jj] = cI[base + jj * NPIX + p];
        s14[jj] = sI[base + jj * NPIX + p];
      }
#pragma unroll
      for (int jj = 0; jj < 6; jj++) {
        c14[KK + jj] = lc[pl][jj];
        s14[KK + jj] = ls[pl][jj];
      }
      // stable odd-even transposition sort of 14
#pragma unroll
      for (int ph = 0; ph < 14; ph++) {
#pragma unroll
        for (int i = (ph & 1); i + 1 < 14; i += 2) {
          if (c14[i] > c14[i + 1]) {
            float tc = c14[i]; c14[i] = c14[i + 1]; c14[i + 1] = tc;
            int ts = s14[i]; s14[i] = s14[i + 1]; s14[i + 1] = ts;
          }
        }
      }
#pragma unroll
      for (int jj = 0; jj < KK; jj++) {
        cO[base + jj * NPIX + p] = c14[jj];
        sO[base + jj * NPIX + p] = s14[jj];
      }
    }
    __syncthreads();
  }
}

// ---------------- attention: 64 px x 4 ch-groups of 16; grid-stride 2 --------
__global__ __launch_bounds__(256) void attn3_k(
    const float* __restrict__ v, const float* __restrict__ cI,
    const int* __restrict__ sI, float* __restrict__ out) {
  int g = threadIdx.x >> 6;      // 0..3
  int pl = threadIdx.x & 63;
  for (int pass = 0; pass < 2; ++pass) {
    int grp = blockIdx.x + pass * NBLK;
    int gpix = grp * 64 + pl;
    int b = gpix >> 16, p = gpix & 0xFFFF;
    int base = b * KK * NPIX;
    float c[KK];
    int off[KK];
#pragma unroll
    for (int j = 0; j < KK; j++) {
      c[j] = cI[base + j * NPIX + p];
      off[j] = sI[base + j * NPIX + p];  // (sy<<8)|sx == sy*256+sx
    }
    float m = c[0];  // sorted ascending -> min cost
    float w[KK];
    float Z = 0.f;
#pragma unroll
    for (int j = 0; j < KK; j++) { w[j] = expf(m - c[j]); Z = Z + w[j]; }
#pragma unroll
    for (int j = 0; j < KK; j++) w[j] = w[j] / Z;
    const float* vb = v + (size_t)b * CVN * NPIX;
    float* ob = out + (size_t)b * CVN * NPIX;
#pragma unroll
    for (int i = 0; i < 16; i++) {
      int cv = g * 16 + i;
      const float* vc = vb + cv * NPIX;
      float acc = 0.f;
#pragma unroll
      for (int j = 0; j < KK; j++) acc = acc + w[j] * vc[off[j]];
      ob[cv * NPIX + p] = acc;
    }
  }
}

extern "C" void kernel_launch(void* const* d_in, const int* in_sizes, int n_in,
                              void* d_out, int out_size, void* d_ws, size_t ws_size,
                              hipStream_t stream) {
  const float* q = (const float*)d_in[0];
  const float* k = (const float*)d_in[1];
  const float* v = (const float*)d_in[2];
  float* out = (float*)d_out;

  // base key: jax.random.key(42) -> (0,42); split -> enc(base,(0,i))
  uint32_t kA0, kA1, kB0, kB1;
  tf2x32(0u, 42u, 0u, 0u, kA0, kA1);
  tf2x32(0u, 42u, 0u, 1u, kB0, kB1);

  // workspace layout (floats): qpad | kpad | costA | costB | sA | sB
  float* qp = (float*)d_ws;
  float* kp = qp + (size_t)2 * CH * CSTR;
  float* cA = kp + (size_t)2 * CH * CSTR;
  float* cB = cA + (size_t)2 * KK * NPIX;
  int* sA = (int*)(cB + (size_t)2 * KK * NPIX);
  int* sB = sA + (size_t)2 * KK * NPIX;

  const int padTotal = 2 * CH * CSTR;
  pad_k<<<(padTotal + 255) / 256, 256, 0, stream>>>(q, k, qp, kp);

  init3_k<<<NBLK, 256, 0, stream>>>(qp, kp, cA, sA, kA0, kA1, kB0, kB1);

  float* ci = cA; int* si = sA;
  float* co = cB; int* so = sB;
  for (int it = 0; it < 5; ++it) {
    iter3_k<<<NBLK, 192, 0, stream>>>(qp, kp, ci, si, co, so, it,
                                      kA0, kA1, kB0, kB1);
    float* tc = ci; ci = co; co = tc;
    int* ts = si; si = so; so = ts;
  }
  attn3_k<<<NBLK, 256, 0, stream>>>(v, ci, si, out);
}

// Round 6
// 1589.156 us; speedup vs baseline: 2.4823x; 1.0848x over previous
//
#include <hip/hip_runtime.h>
#include <stdint.h>

#define HW 256
#define HWP 258
#define CH 32
#define CVN 64
#define NPIX (HW*HW)
#define KK 8
#define CSTRT (HWP*HWP)

// PRNG (verified r3): partitionable threefry + SPLIT-key randint.
// r5 post-mortem: latency-bound (VALU 6.8%, HBM 12%) — 12B scattered taps.
// r6: (y,x,c)-interleaved q/k/v layouts -> contiguous float4 patch reads,
//     one cand/thread, full grid (L3-resident working set, no lockstep needed).

// ---------------- Threefry-2x32 (JAX-compatible) ----------------
__host__ __device__ __forceinline__ void tf2x32(uint32_t k0, uint32_t k1,
                                                uint32_t x0, uint32_t x1,
                                                uint32_t &o0, uint32_t &o1) {
  const uint32_t ks2 = k0 ^ k1 ^ 0x1BD11BDAu;
  x0 += k0; x1 += k1;
#define TFR(r) x0 += x1; x1 = (x1 << (r)) | (x1 >> (32 - (r))); x1 ^= x0;
  TFR(13) TFR(15) TFR(26) TFR(6)
  x0 += k1;  x1 += ks2 + 1u;
  TFR(17) TFR(29) TFR(16) TFR(24)
  x0 += ks2; x1 += k0 + 2u;
  TFR(13) TFR(15) TFR(26) TFR(6)
  x0 += k0;  x1 += k1 + 3u;
  TFR(17) TFR(29) TFR(16) TFR(24)
  x0 += k1;  x1 += ks2 + 4u;
  TFR(13) TFR(15) TFR(26) TFR(6)
  x0 += ks2; x1 += k0 + 5u;
#undef TFR
  o0 = x0; o1 = x1;
}

__device__ __forceinline__ uint32_t tfbits(uint32_t k0, uint32_t k1, uint32_t idx) {
  uint32_t a, b;
  tf2x32(k0, k1, 0u, idx, a, b);
  return a ^ b;
}

// ------- tiled transpose+pad: (C=32, 65536) -> padded (258,258,32) -------
__global__ __launch_bounds__(256) void tpad_k(const float* __restrict__ src,
                                              float* __restrict__ dst) {
  __shared__ float tile[CH][65];
  int t = blockIdx.x;              // 2048 tiles: b*1024 + tile-of-64px
  int b = t >> 10;
  int p0 = (t & 1023) * 64;
  int tid = threadIdx.x;
  const float* sb = src + (size_t)b * CH * NPIX;
#pragma unroll
  for (int i = 0; i < 8; i++) {
    int idx = i * 256 + tid;
    int c = idx >> 6, px = idx & 63;
    tile[c][px] = sb[c * NPIX + p0 + px];
  }
  __syncthreads();
  float* db = dst + (size_t)b * CSTRT * CH;
#pragma unroll
  for (int i = 0; i < 8; i++) {
    int idx = i * 256 + tid;
    int px = idx >> 5, c = idx & 31;
    int p = p0 + px;
    int y = p >> 8, x = p & 255;
    db[((size_t)(y + 1) * HWP + (x + 1)) * CH + c] = tile[c][px];
  }
}

// ------- tiled transpose: v (64, 65536) -> vp (65536, 64) -------
__global__ __launch_bounds__(256) void vtr_k(const float* __restrict__ v,
                                             float* __restrict__ vp) {
  __shared__ float tile[CVN][65];
  int t = blockIdx.x;              // 2048 tiles
  int b = t >> 10;
  int p0 = (t & 1023) * 64;
  int tid = threadIdx.x;
  const float* sb = v + (size_t)b * CVN * NPIX;
#pragma unroll
  for (int i = 0; i < 16; i++) {
    int idx = i * 256 + tid;
    int c = idx >> 6, px = idx & 63;
    tile[c][px] = sb[c * NPIX + p0 + px];
  }
  __syncthreads();
  float* db = vp + (size_t)b * NPIX * CVN;
#pragma unroll
  for (int i = 0; i < 16; i++) {
    int idx = i * 256 + tid;
    int px = idx >> 6, c = idx & 63;
    db[(size_t)(p0 + px) * CVN + c] = tile[c][px];
  }
}

// ---------------- patch cost on (y,x,c) layout, bit-exact ----------------
// Per-tap accumulator sums over c sequentially (float4 load, ordered adds);
// final reduction in reference's flat (dy,dx) order. contract off.
__device__ __forceinline__ float patch_cost_t(const float* __restrict__ qb2,
                                              const float* __restrict__ kb2,
                                              int y, int x, int sy, int sx) {
#pragma clang fp contract(off)
  float S[3][3];
#pragma unroll
  for (int dy = 0; dy < 3; dy++)
#pragma unroll
    for (int dx = 0; dx < 3; dx++) S[dy][dx] = 0.f;
  const float* qb = qb2 + ((size_t)y * HWP + x) * CH;
  const float* kb = kb2 + ((size_t)sy * HWP + sx) * CH;
#pragma unroll 2
  for (int ch = 0; ch < CH; ch += 4) {
#pragma unroll
    for (int dy = 0; dy < 3; dy++) {
#pragma unroll
      for (int dx = 0; dx < 3; dx++) {
        const float4 qv = *(const float4*)(qb + (dy * HWP + dx) * CH + ch);
        const float4 kv = *(const float4*)(kb + (dy * HWP + dx) * CH + ch);
        float d;
        d = qv.x - kv.x; S[dy][dx] = S[dy][dx] + d * d;
        d = qv.y - kv.y; S[dy][dx] = S[dy][dx] + d * d;
        d = qv.z - kv.z; S[dy][dx] = S[dy][dx] + d * d;
        d = qv.w - kv.w; S[dy][dx] = S[dy][dx] + d * d;
      }
    }
  }
  float cost = 0.f;
#pragma unroll
  for (int dy = 0; dy < 3; dy++)
#pragma unroll
    for (int dx = 0; dx < 3; dx++) cost = cost + S[dy][dx];
  return cost;
}

// ---------------- init: 32 px x 8 cand per 256-thread block ----------------
__global__ __launch_bounds__(256) void init4_k(
    const float* __restrict__ qp2, const float* __restrict__ kp2,
    float* __restrict__ cO, int* __restrict__ sO,
    uint32_t kA0, uint32_t kA1, uint32_t kB0, uint32_t kB1) {
  __shared__ float lc[32][KK + 1];
  __shared__ int ls[32][KK + 1];
  int j = threadIdx.x >> 5;      // candidate 0..7
  int pl = threadIdx.x & 31;
  int gpix = blockIdx.x * 32 + pl;
  int b = gpix >> 16, p = gpix & 0xFFFF;
  int y = p >> 8, x = p & 255;
  uint32_t k0 = b ? kB0 : kA0, k1 = b ? kB1 : kA1;
  // fold_in(key,10000/10001); span=256 -> mult 0 -> lower bits only (k2 of split)
  uint32_t f0, f1, ky0, ky1, kx0, kx1;
  tf2x32(k0, k1, 0u, 10000u, f0, f1);
  tf2x32(f0, f1, 0u, 1u, ky0, ky1);
  tf2x32(k0, k1, 0u, 10001u, f0, f1);
  tf2x32(f0, f1, 0u, 1u, kx0, kx1);
  uint32_t cand = (uint32_t)(j * NPIX + p);
  int sy = (int)(tfbits(ky0, ky1, cand) & 255u);
  int sx = (int)(tfbits(kx0, kx1, cand) & 255u);
  const float* qpb = qp2 + (size_t)b * CSTRT * CH;
  const float* kpb = kp2 + (size_t)b * CSTRT * CH;
  float c = patch_cost_t(qpb, kpb, y, x, sy, sx);
  lc[pl][j] = c;
  ls[pl][j] = (sy << 8) | sx;
  __syncthreads();
  if (threadIdx.x < 32) {
    float c8[KK];
    int s8[KK];
#pragma unroll
    for (int jj = 0; jj < KK; jj++) { c8[jj] = lc[pl][jj]; s8[jj] = ls[pl][jj]; }
    // stable odd-even transposition sort (== lax.top_k tie semantics)
#pragma unroll
    for (int ph = 0; ph < KK; ph++) {
#pragma unroll
      for (int i = (ph & 1); i + 1 < KK; i += 2) {
        if (c8[i] > c8[i + 1]) {
          float tc = c8[i]; c8[i] = c8[i + 1]; c8[i + 1] = tc;
          int ts = s8[i]; s8[i] = s8[i + 1]; s8[i + 1] = ts;
        }
      }
    }
    int base = b * KK * NPIX;
#pragma unroll
    for (int jj = 0; jj < KK; jj++) {
      cO[base + jj * NPIX + p] = c8[jj];
      sO[base + jj * NPIX + p] = s8[jj];
    }
  }
}

// ---------------- prop/rand candidate helpers (r3-verified) ----------------
__device__ __forceinline__ void prop_cand(const int* __restrict__ sI, int base,
                                          int y, int x, int c, int &nsy, int &nsx) {
  int np;
  if (c == 0)      np = (y << 8) | ((x + HW - 1) & (HW - 1));
  else if (c == 1) np = (y << 8) | ((x + 1) & (HW - 1));
  else if (c == 2) np = (((y + HW - 1) & (HW - 1)) << 8) | x;
  else             np = (((y + 1) & (HW - 1)) << 8) | x;
  int sv = sI[base + np];
  if (c == 0)      { nsy = sv >> 8;       nsx = (sv & 255) + 1; }
  else if (c == 1) { nsy = sv >> 8;       nsx = (sv & 255) - 1; }
  else if (c == 2) { nsy = (sv >> 8) + 1; nsx = sv & 255; }
  else             { nsy = (sv >> 8) - 1; nsx = sv & 255; }
}

__device__ __forceinline__ void rand_cand(uint32_t kit0, uint32_t kit1, int s,
                                          uint32_t p, int by, int bx,
                                          int &nsy, int &nsx) {
  uint32_t f0, f1, h0, h1, l0, l1, hi, lo;
  tf2x32(kit0, kit1, 0u, (uint32_t)(2 * s), f0, f1);
  tf2x32(f0, f1, 0u, 0u, h0, h1);
  tf2x32(f0, f1, 0u, 1u, l0, l1);
  hi = tfbits(h0, h1, p); lo = tfbits(l0, l1, p);
  int offy = (s == 0) ? (int)(((hi % 257u) + (lo % 257u)) % 257u)
                      : (int)((((hi % 129u) * 16u) + (lo % 129u)) % 129u);
  tf2x32(kit0, kit1, 0u, (uint32_t)(2 * s + 1), f0, f1);
  tf2x32(f0, f1, 0u, 0u, h0, h1);
  tf2x32(f0, f1, 0u, 1u, l0, l1);
  hi = tfbits(h0, h1, p); lo = tfbits(l0, l1, p);
  int offx = (s == 0) ? (int)(((hi % 257u) + (lo % 257u)) % 257u)
                      : (int)((((hi % 129u) * 16u) + (lo % 129u)) % 129u);
  int rad = (s == 0) ? 128 : 64;
  nsy = by + (offy - rad);
  nsx = bx + (offx - rad);
}

// ---------------- iter: 32 px x 6 cand per 192-thread block ----------------
__global__ __launch_bounds__(192) void iter4_k(
    const float* __restrict__ qp2, const float* __restrict__ kp2,
    const float* __restrict__ cI, const int* __restrict__ sI,
    float* __restrict__ cO, int* __restrict__ sO,
    int it, uint32_t kA0, uint32_t kA1, uint32_t kB0, uint32_t kB1) {
  __shared__ float lc[32][7];
  __shared__ int ls[32][7];
  int j = threadIdx.x >> 5;      // candidate 0..5
  int pl = threadIdx.x & 31;
  int gpix = blockIdx.x * 32 + pl;
  int b = gpix >> 16, p = gpix & 0xFFFF;
  int y = p >> 8, x = p & 255;
  int base = b * KK * NPIX;
  int nsy, nsx;
  if (j < 4) {
    prop_cand(sI, base, y, x, j, nsy, nsx);
  } else {
    int svc = sI[base + p];
    int by = svc >> 8, bx = svc & 255;
    uint32_t k0 = b ? kB0 : kA0, k1 = b ? kB1 : kA1;
    uint32_t kit0, kit1;
    tf2x32(k0, k1, 0u, (uint32_t)it, kit0, kit1);  // fold_in(key, it)
    rand_cand(kit0, kit1, j - 4, (uint32_t)p, by, bx, nsy, nsx);
  }
  nsy = min(max(nsy, 0), HW - 1);
  nsx = min(max(nsx, 0), HW - 1);
  const float* qpb = qp2 + (size_t)b * CSTRT * CH;
  const float* kpb = kp2 + (size_t)b * CSTRT * CH;
  float c = patch_cost_t(qpb, kpb, y, x, nsy, nsx);
  lc[pl][j] = c;
  ls[pl][j] = (nsy << 8) | nsx;
  __syncthreads();
  if (threadIdx.x < 32) {
    float c14[KK + 6];
    int s14[KK + 6];
#pragma unroll
    for (int jj = 0; jj < KK; jj++) {
      c14[jj] = cI[base + jj * NPIX + p];
      s14[jj] = sI[base + jj * NPIX + p];
    }
#pragma unroll
    for (int jj = 0; jj < 6; jj++) {
      c14[KK + jj] = lc[pl][jj];
      s14[KK + jj] = ls[pl][jj];
    }
    // stable odd-even transposition sort of 14
#pragma unroll
    for (int ph = 0; ph < 14; ph++) {
#pragma unroll
      for (int i = (ph & 1); i + 1 < 14; i += 2) {
        if (c14[i] > c14[i + 1]) {
          float tc = c14[i]; c14[i] = c14[i + 1]; c14[i + 1] = tc;
          int ts = s14[i]; s14[i] = s14[i + 1]; s14[i + 1] = ts;
        }
      }
    }
#pragma unroll
    for (int jj = 0; jj < KK; jj++) {
      cO[base + jj * NPIX + p] = c14[jj];
      sO[base + jj * NPIX + p] = s14[jj];
    }
  }
}

// ------- attention from transposed vp (px, 64ch): 64 px x 4 grp -------
__global__ __launch_bounds__(256) void attn4_k(
    const float* __restrict__ vp, const float* __restrict__ cI,
    const int* __restrict__ sI, float* __restrict__ out) {
  int g = threadIdx.x >> 6;      // 0..3 -> channels g*16..g*16+15
  int pl = threadIdx.x & 63;
  int gpix = blockIdx.x * 64 + pl;
  int b = gpix >> 16, p = gpix & 0xFFFF;
  int base = b * KK * NPIX;
  float c[KK];
  int off[KK];
#pragma unroll
  for (int j = 0; j < KK; j++) {
    c[j] = cI[base + j * NPIX + p];
    off[j] = sI[base + j * NPIX + p];  // (sy<<8)|sx == sy*256+sx
  }
  float m = c[0];
  float w[KK];
  float Z = 0.f;
#pragma unroll
  for (int j = 0; j < KK; j++) { w[j] = expf(m - c[j]); Z = Z + w[j]; }
#pragma unroll
  for (int j = 0; j < KK; j++) w[j] = w[j] / Z;
  const float* vb = vp + (size_t)b * NPIX * CVN + g * 16;
  float acc[16];
#pragma unroll
  for (int i = 0; i < 16; i++) acc[i] = 0.f;
#pragma unroll
  for (int j = 0; j < KK; j++) {
    const float4* vr = (const float4*)(vb + (size_t)off[j] * CVN);
#pragma unroll
    for (int t = 0; t < 4; t++) {
      float4 vv = vr[t];
      acc[t * 4 + 0] = acc[t * 4 + 0] + w[j] * vv.x;
      acc[t * 4 + 1] = acc[t * 4 + 1] + w[j] * vv.y;
      acc[t * 4 + 2] = acc[t * 4 + 2] + w[j] * vv.z;
      acc[t * 4 + 3] = acc[t * 4 + 3] + w[j] * vv.w;
    }
  }
  float* ob = out + (size_t)b * CVN * NPIX;
#pragma unroll
  for (int i = 0; i < 16; i++) ob[(size_t)(g * 16 + i) * NPIX + p] = acc[i];
}

// ------- attention fallback from plane-layout v (if ws too small) -------
__global__ __launch_bounds__(256) void attn4p_k(
    const float* __restrict__ v, const float* __restrict__ cI,
    const int* __restrict__ sI, float* __restrict__ out) {
  int g = threadIdx.x >> 6;
  int pl = threadIdx.x & 63;
  int gpix = blockIdx.x * 64 + pl;
  int b = gpix >> 16, p = gpix & 0xFFFF;
  int base = b * KK * NPIX;
  float c[KK];
  int off[KK];
#pragma unroll
  for (int j = 0; j < KK; j++) {
    c[j] = cI[base + j * NPIX + p];
    off[j] = sI[base + j * NPIX + p];
  }
  float m = c[0];
  float w[KK];
  float Z = 0.f;
#pragma unroll
  for (int j = 0; j < KK; j++) { w[j] = expf(m - c[j]); Z = Z + w[j]; }
#pragma unroll
  for (int j = 0; j < KK; j++) w[j] = w[j] / Z;
  const float* vb = v + (size_t)b * CVN * NPIX;
  float* ob = out + (size_t)b * CVN * NPIX;
#pragma unroll
  for (int i = 0; i < 16; i++) {
    int cv = g * 16 + i;
    const float* vc = vb + (size_t)cv * NPIX;
    float acc = 0.f;
#pragma unroll
    for (int j = 0; j < KK; j++) acc = acc + w[j] * vc[off[j]];
    ob[(size_t)cv * NPIX + p] = acc;
  }
}

extern "C" void kernel_launch(void* const* d_in, const int* in_sizes, int n_in,
                              void* d_out, int out_size, void* d_ws, size_t ws_size,
                              hipStream_t stream) {
  const float* q = (const float*)d_in[0];
  const float* k = (const float*)d_in[1];
  const float* v = (const float*)d_in[2];
  float* out = (float*)d_out;

  // base key: jax.random.key(42) -> (0,42); split -> enc(base,(0,i))
  uint32_t kA0, kA1, kB0, kB1;
  tf2x32(0u, 42u, 0u, 0u, kA0, kA1);
  tf2x32(0u, 42u, 0u, 1u, kB0, kB1);

  // ws layout (floats): qp2 | kp2 | cA | cB | sA | sB | [vp]
  const size_t szPad = (size_t)2 * CSTRT * CH;     // 4,260,096
  const size_t szCS  = (size_t)2 * KK * NPIX;      // 1,048,576
  const size_t szVp  = (size_t)2 * NPIX * CVN;     // 8,388,608
  float* qp2 = (float*)d_ws;
  float* kp2 = qp2 + szPad;
  float* cA = kp2 + szPad;
  float* cB = cA + szCS;
  int* sA = (int*)(cB + szCS);
  int* sB = sA + szCS;
  float* vp = (float*)(sB + szCS);
  bool use_vp = ws_size >= (2 * szPad + 4 * szCS + szVp) * sizeof(float);

  // zero padded borders, then transpose-fill interiors
  hipMemsetAsync(qp2, 0, szPad * sizeof(float), stream);
  hipMemsetAsync(kp2, 0, szPad * sizeof(float), stream);
  tpad_k<<<2048, 256, 0, stream>>>(q, qp2);
  tpad_k<<<2048, 256, 0, stream>>>(k, kp2);
  if (use_vp) vtr_k<<<2048, 256, 0, stream>>>(v, vp);

  init4_k<<<4096, 256, 0, stream>>>(qp2, kp2, cA, sA, kA0, kA1, kB0, kB1);

  float* ci = cA; int* si = sA;
  float* co = cB; int* so = sB;
  for (int it = 0; it < 5; ++it) {
    iter4_k<<<4096, 192, 0, stream>>>(qp2, kp2, ci, si, co, so, it,
                                      kA0, kA1, kB0, kB1);
    float* tc = ci; ci = co; co = tc;
    int* ts = si; si = so; so = ts;
  }
  if (use_vp) attn4_k<<<2048, 256, 0, stream>>>(vp, ci, si, out);
  else        attn4p_k<<<2048, 256, 0, stream>>>(v, ci, si, out);
}

// Round 7
// 1201.296 us; speedup vs baseline: 3.2838x; 1.3229x over previous
//
#include <hip/hip_runtime.h>
#include <stdint.h>

#define HW 256
#define HWP 258
#define CH 32
#define CVN 64
#define NPIX (HW*HW)
#define KK 8
#define CSTRT (HWP*HWP)

// PRNG (verified r3): partitionable threefry + SPLIT-key randint.
// r6 post-mortem: random 1152B/candidate gathers all miss L2 (17MB set) ->
//   1.37GB fetch at ~3.5TB/s L2-fill ceiling. r7: band candidates by sy>>5
//   (1MB/batch band = L2-resident), q-tile in LDS, LDS counting-sort bins.

// ---------------- Threefry-2x32 (JAX-compatible) ----------------
__host__ __device__ __forceinline__ void tf2x32(uint32_t k0, uint32_t k1,
                                                uint32_t x0, uint32_t x1,
                                                uint32_t &o0, uint32_t &o1) {
  const uint32_t ks2 = k0 ^ k1 ^ 0x1BD11BDAu;
  x0 += k0; x1 += k1;
#define TFR(r) x0 += x1; x1 = (x1 << (r)) | (x1 >> (32 - (r))); x1 ^= x0;
  TFR(13) TFR(15) TFR(26) TFR(6)
  x0 += k1;  x1 += ks2 + 1u;
  TFR(17) TFR(29) TFR(16) TFR(24)
  x0 += ks2; x1 += k0 + 2u;
  TFR(13) TFR(15) TFR(26) TFR(6)
  x0 += k0;  x1 += k1 + 3u;
  TFR(17) TFR(29) TFR(16) TFR(24)
  x0 += k1;  x1 += ks2 + 4u;
  TFR(13) TFR(15) TFR(26) TFR(6)
  x0 += ks2; x1 += k0 + 5u;
#undef TFR
  o0 = x0; o1 = x1;
}

__device__ __forceinline__ uint32_t tfbits(uint32_t k0, uint32_t k1, uint32_t idx) {
  uint32_t a, b;
  tf2x32(k0, k1, 0u, idx, a, b);
  return a ^ b;
}

// ------- tiled transpose+pad: (C=32, 65536) -> padded (258,258,32) -------
__global__ __launch_bounds__(256) void tpad_k(const float* __restrict__ src,
                                              float* __restrict__ dst) {
  __shared__ float tile[CH][65];
  int t = blockIdx.x;              // 2048 tiles: b*1024 + tile-of-64px
  int b = t >> 10;
  int p0 = (t & 1023) * 64;
  int tid = threadIdx.x;
  const float* sb = src + (size_t)b * CH * NPIX;
#pragma unroll
  for (int i = 0; i < 8; i++) {
    int idx = i * 256 + tid;
    int c = idx >> 6, px = idx & 63;
    tile[c][px] = sb[c * NPIX + p0 + px];
  }
  __syncthreads();
  float* db = dst + (size_t)b * CSTRT * CH;
#pragma unroll
  for (int i = 0; i < 8; i++) {
    int idx = i * 256 + tid;
    int px = idx >> 5, c = idx & 31;
    int p = p0 + px;
    int y = p >> 8, x = p & 255;
    db[((size_t)(y + 1) * HWP + (x + 1)) * CH + c] = tile[c][px];
  }
}

// ------- tiled transpose: v (64, 65536) -> vp (65536, 64) -------
__global__ __launch_bounds__(256) void vtr_k(const float* __restrict__ v,
                                             float* __restrict__ vp) {
  __shared__ float tile[CVN][65];
  int t = blockIdx.x;              // 2048 tiles
  int b = t >> 10;
  int p0 = (t & 1023) * 64;
  int tid = threadIdx.x;
  const float* sb = v + (size_t)b * CVN * NPIX;
#pragma unroll
  for (int i = 0; i < 16; i++) {
    int idx = i * 256 + tid;
    int c = idx >> 6, px = idx & 63;
    tile[c][px] = sb[c * NPIX + p0 + px];
  }
  __syncthreads();
  float* db = vp + (size_t)b * NPIX * CVN;
#pragma unroll
  for (int i = 0; i < 16; i++) {
    int idx = i * 256 + tid;
    int px = idx >> 6, c = idx & 63;
    db[(size_t)(p0 + px) * CVN + c] = tile[c][px];
  }
}

// ---- cost from LDS q-tile (swizzled) + global k, bit-exact r6 order ----
// qt: [3][66][32] floats, channel rotated by 4*(xx&7) within each pixel.
__device__ __forceinline__ float cost_lds(const float* __restrict__ qt, int pl,
                                          const float* __restrict__ kb2,
                                          int sy, int sx) {
#pragma clang fp contract(off)
  float S[3][3];
#pragma unroll
  for (int dy = 0; dy < 3; dy++)
#pragma unroll
    for (int dx = 0; dx < 3; dx++) S[dy][dx] = 0.f;
  const float* kb = kb2 + ((size_t)sy * HWP + sx) * CH;
#pragma unroll 2
  for (int ch = 0; ch < CH; ch += 4) {
#pragma unroll
    for (int dy = 0; dy < 3; dy++) {
#pragma unroll
      for (int dx = 0; dx < 3; dx++) {
        int xx = pl + dx;
        const float4 qv = *(const float4*)(&qt[(dy * 66 + xx) * 32 +
                                              ((ch + 4 * (xx & 7)) & 31)]);
        const float4 kv = *(const float4*)(kb + (dy * HWP + dx) * CH + ch);
        float d;
        d = qv.x - kv.x; S[dy][dx] = S[dy][dx] + d * d;
        d = qv.y - kv.y; S[dy][dx] = S[dy][dx] + d * d;
        d = qv.z - kv.z; S[dy][dx] = S[dy][dx] + d * d;
        d = qv.w - kv.w; S[dy][dx] = S[dy][dx] + d * d;
      }
    }
  }
  float cost = 0.f;
#pragma unroll
  for (int dy = 0; dy < 3; dy++)
#pragma unroll
    for (int dx = 0; dx < 3; dx++) cost = cost + S[dy][dx];
  return cost;
}

// load q tile rows y..y+2 (padded), cols x0..x0+65 (padded), swizzled
template<int NT>
__device__ __forceinline__ void load_qtile(const float* __restrict__ qpb,
                                           float* __restrict__ qt,
                                           int y, int x0, int tid) {
  for (int i = tid; i < 3 * 66 * 8; i += NT) {
    int c4 = i & 7;
    int xx = (i >> 3) % 66;
    int dy = (i >> 3) / 66;
    float4 v = *(const float4*)(qpb + ((size_t)(y + dy) * HWP + (x0 + xx)) * CH + c4 * 4);
    *(float4*)(&qt[(dy * 66 + xx) * 32 + ((c4 * 4 + 4 * (xx & 7)) & 31)]) = v;
  }
}

// ---------------- init: 64px block, banded candidate eval ----------------
__global__ __launch_bounds__(256) void init5_k(
    const float* __restrict__ qp2, const float* __restrict__ kp2,
    float* __restrict__ cO, int* __restrict__ sO,
    uint32_t kA0, uint32_t kA1, uint32_t kB0, uint32_t kB1) {
  __shared__ float qt[3 * 66 * 32];
  __shared__ uint32_t ent[512];
  __shared__ float lc[64][KK];
  __shared__ int lsv[64][KK];
  __shared__ int bcnt[8], bstart[9], boff[8];
  int tid = threadIdx.x;
  int grp = blockIdx.x;
  int b = grp >> 10;
  int gp = (grp & 1023) * 64;
  int y = gp >> 8, x0 = gp & 255;
  const float* qpb = qp2 + (size_t)b * CSTRT * CH;
  const float* kpb = kp2 + (size_t)b * CSTRT * CH;
  load_qtile<256>(qpb, qt, y, x0, tid);
  if (tid < 8) bcnt[tid] = 0;
  __syncthreads();

  // keys: fold_in(key,10000/10001); span=256 -> lower bits only (k2 of split)
  uint32_t k0 = b ? kB0 : kA0, k1 = b ? kB1 : kA1;
  uint32_t f0, f1, ky0, ky1, kx0, kx1;
  tf2x32(k0, k1, 0u, 10000u, f0, f1);
  tf2x32(f0, f1, 0u, 1u, ky0, ky1);
  tf2x32(k0, k1, 0u, 10001u, f0, f1);
  tf2x32(f0, f1, 0u, 1u, kx0, kx1);

  uint32_t my[2];
  int myband[2];
#pragma unroll
  for (int e = 0; e < 2; e++) {
    int idx = tid + e * 256;       // 0..511
    int pl = idx & 63, j = idx >> 6;
    int p = (y << 8) | (x0 + pl);
    uint32_t cand = (uint32_t)(j * NPIX + p);
    int sy = (int)(tfbits(ky0, ky1, cand) & 255u);
    int sx = (int)(tfbits(kx0, kx1, cand) & 255u);
    my[e] = ((uint32_t)sy << 17) | ((uint32_t)sx << 9) | ((uint32_t)pl << 3) | (uint32_t)j;
    myband[e] = sy >> 5;
    atomicAdd(&bcnt[myband[e]], 1);
  }
  __syncthreads();
  if (tid == 0) {
    int s = 0;
#pragma unroll
    for (int i = 0; i < 8; i++) { bstart[i] = s; boff[i] = s; s += bcnt[i]; }
    bstart[8] = s;
  }
  __syncthreads();
#pragma unroll
  for (int e = 0; e < 2; e++) {
    int pos = atomicAdd(&boff[myband[e]], 1);
    ent[pos] = my[e];
  }
  __syncthreads();

  for (int band = 0; band < 8; band++) {
    int s = bstart[band], t = bstart[band + 1];
    for (int i = s + tid; i < t; i += 256) {
      uint32_t en = ent[i];
      int j = en & 7, pl = (en >> 3) & 63;
      int sx = (en >> 9) & 255, sy = (en >> 17) & 255;
      float c = cost_lds(qt, pl, kpb, sy, sx);
      lc[pl][j] = c;
      lsv[pl][j] = (sy << 8) | sx;
    }
    __syncthreads();
  }

  if (tid < 64) {
    int pl = tid;
    float c8[KK];
    int s8[KK];
#pragma unroll
    for (int jj = 0; jj < KK; jj++) { c8[jj] = lc[pl][jj]; s8[jj] = lsv[pl][jj]; }
    // stable odd-even transposition sort (== lax.top_k tie semantics)
#pragma unroll
    for (int ph = 0; ph < KK; ph++) {
#pragma unroll
      for (int i = (ph & 1); i + 1 < KK; i += 2) {
        if (c8[i] > c8[i + 1]) {
          float tc = c8[i]; c8[i] = c8[i + 1]; c8[i + 1] = tc;
          int ts = s8[i]; s8[i] = s8[i + 1]; s8[i + 1] = ts;
        }
      }
    }
    int p = (y << 8) | (x0 + pl);
    int base = b * KK * NPIX;
#pragma unroll
    for (int jj = 0; jj < KK; jj++) {
      cO[base + jj * NPIX + p] = c8[jj];
      sO[base + jj * NPIX + p] = s8[jj];
    }
  }
}

// ---------------- prop/rand candidate helpers (r3-verified) ----------------
__device__ __forceinline__ void prop_cand(const int* __restrict__ sI, int base,
                                          int y, int x, int c, int &nsy, int &nsx) {
  int np;
  if (c == 0)      np = (y << 8) | ((x + HW - 1) & (HW - 1));
  else if (c == 1) np = (y << 8) | ((x + 1) & (HW - 1));
  else if (c == 2) np = (((y + HW - 1) & (HW - 1)) << 8) | x;
  else             np = (((y + 1) & (HW - 1)) << 8) | x;
  int sv = sI[base + np];
  if (c == 0)      { nsy = sv >> 8;       nsx = (sv & 255) + 1; }
  else if (c == 1) { nsy = sv >> 8;       nsx = (sv & 255) - 1; }
  else if (c == 2) { nsy = (sv >> 8) + 1; nsx = sv & 255; }
  else             { nsy = (sv >> 8) - 1; nsx = sv & 255; }
}

__device__ __forceinline__ void rand_cand(uint32_t kit0, uint32_t kit1, int s,
                                          uint32_t p, int by, int bx,
                                          int &nsy, int &nsx) {
  uint32_t f0, f1, h0, h1, l0, l1, hi, lo;
  tf2x32(kit0, kit1, 0u, (uint32_t)(2 * s), f0, f1);
  tf2x32(f0, f1, 0u, 0u, h0, h1);
  tf2x32(f0, f1, 0u, 1u, l0, l1);
  hi = tfbits(h0, h1, p); lo = tfbits(l0, l1, p);
  int offy = (s == 0) ? (int)(((hi % 257u) + (lo % 257u)) % 257u)
                      : (int)((((hi % 129u) * 16u) + (lo % 129u)) % 129u);
  tf2x32(kit0, kit1, 0u, (uint32_t)(2 * s + 1), f0, f1);
  tf2x32(f0, f1, 0u, 0u, h0, h1);
  tf2x32(f0, f1, 0u, 1u, l0, l1);
  hi = tfbits(h0, h1, p); lo = tfbits(l0, l1, p);
  int offx = (s == 0) ? (int)(((hi % 257u) + (lo % 257u)) % 257u)
                      : (int)((((hi % 129u) * 16u) + (lo % 129u)) % 129u);
  int rad = (s == 0) ? 128 : 64;
  nsy = by + (offy - rad);
  nsx = bx + (offx - rad);
}

// ---------------- iter: 64px block x 6 cand, banded ----------------
__global__ __launch_bounds__(192) void iter5_k(
    const float* __restrict__ qp2, const float* __restrict__ kp2,
    const float* __restrict__ cI, const int* __restrict__ sI,
    float* __restrict__ cO, int* __restrict__ sO,
    int it, uint32_t kA0, uint32_t kA1, uint32_t kB0, uint32_t kB1) {
  __shared__ float qt[3 * 66 * 32];
  __shared__ uint32_t ent[384];
  __shared__ float lc[64][6];
  __shared__ int lsv[64][6];
  __shared__ int bcnt[8], bstart[9], boff[8];
  int tid = threadIdx.x;
  int grp = blockIdx.x;
  int b = grp >> 10;
  int gp = (grp & 1023) * 64;
  int y = gp >> 8, x0 = gp & 255;
  int base = b * KK * NPIX;
  const float* qpb = qp2 + (size_t)b * CSTRT * CH;
  const float* kpb = kp2 + (size_t)b * CSTRT * CH;
  load_qtile<192>(qpb, qt, y, x0, tid);
  if (tid < 8) bcnt[tid] = 0;
  __syncthreads();

  uint32_t k0 = b ? kB0 : kA0, k1 = b ? kB1 : kA1;
  uint32_t kit0, kit1;
  tf2x32(k0, k1, 0u, (uint32_t)it, kit0, kit1);  // fold_in(key, it)

  uint32_t my[2];
  int myband[2];
#pragma unroll
  for (int e = 0; e < 2; e++) {
    int idx = tid + e * 192;       // 0..383
    int pl = idx & 63, j = idx >> 6;
    int x = x0 + pl;
    int p = (y << 8) | x;
    int nsy, nsx;
    if (j < 4) {
      prop_cand(sI, base, y, x, j, nsy, nsx);
    } else {
      int svc = sI[base + p];
      rand_cand(kit0, kit1, j - 4, (uint32_t)p, svc >> 8, svc & 255, nsy, nsx);
    }
    nsy = min(max(nsy, 0), HW - 1);
    nsx = min(max(nsx, 0), HW - 1);
    my[e] = ((uint32_t)nsy << 17) | ((uint32_t)nsx << 9) | ((uint32_t)pl << 3) | (uint32_t)j;
    myband[e] = nsy >> 5;
    atomicAdd(&bcnt[myband[e]], 1);
  }
  __syncthreads();
  if (tid == 0) {
    int s = 0;
#pragma unroll
    for (int i = 0; i < 8; i++) { bstart[i] = s; boff[i] = s; s += bcnt[i]; }
    bstart[8] = s;
  }
  __syncthreads();
#pragma unroll
  for (int e = 0; e < 2; e++) {
    int pos = atomicAdd(&boff[myband[e]], 1);
    ent[pos] = my[e];
  }
  __syncthreads();

  for (int band = 0; band < 8; band++) {
    int s = bstart[band], t = bstart[band + 1];
    for (int i = s + tid; i < t; i += 192) {
      uint32_t en = ent[i];
      int j = en & 7, pl = (en >> 3) & 63;
      int sx = (en >> 9) & 255, sy = (en >> 17) & 255;
      float c = cost_lds(qt, pl, kpb, sy, sx);
      lc[pl][j] = c;
      lsv[pl][j] = (sy << 8) | sx;
    }
    __syncthreads();
  }

  if (tid < 64) {
    int pl = tid;
    int p = (y << 8) | (x0 + pl);
    float c14[KK + 6];
    int s14[KK + 6];
#pragma unroll
    for (int jj = 0; jj < KK; jj++) {
      c14[jj] = cI[base + jj * NPIX + p];
      s14[jj] = sI[base + jj * NPIX + p];
    }
#pragma unroll
    for (int jj = 0; jj < 6; jj++) {
      c14[KK + jj] = lc[pl][jj];
      s14[KK + jj] = lsv[pl][jj];
    }
    // stable odd-even transposition sort of 14
#pragma unroll
    for (int ph = 0; ph < 14; ph++) {
#pragma unroll
      for (int i = (ph & 1); i + 1 < 14; i += 2) {
        if (c14[i] > c14[i + 1]) {
          float tc = c14[i]; c14[i] = c14[i + 1]; c14[i + 1] = tc;
          int ts = s14[i]; s14[i] = s14[i + 1]; s14[i + 1] = ts;
        }
      }
    }
#pragma unroll
    for (int jj = 0; jj < KK; jj++) {
      cO[base + jj * NPIX + p] = c14[jj];
      sO[base + jj * NPIX + p] = s14[jj];
    }
  }
}

// ------- attention, banded over 16-row bands of v (px,64) layout -------
__global__ __launch_bounds__(256) void attn5_k(
    const float* __restrict__ vp, const float* __restrict__ cI,
    const int* __restrict__ sI, float* __restrict__ out) {
  int g = threadIdx.x >> 6;      // 0..3 -> channels g*16..g*16+15
  int pl = threadIdx.x & 63;
  int gpix = blockIdx.x * 64 + pl;
  int b = gpix >> 16, p = gpix & 0xFFFF;
  int base = b * KK * NPIX;
  float c[KK];
  int off[KK];
#pragma unroll
  for (int j = 0; j < KK; j++) {
    c[j] = cI[base + j * NPIX + p];
    off[j] = sI[base + j * NPIX + p];
  }
  float m = c[0];
  float w[KK];
  float Z = 0.f;
#pragma unroll
  for (int j = 0; j < KK; j++) { w[j] = expf(m - c[j]); Z = Z + w[j]; }
#pragma unroll
  for (int j = 0; j < KK; j++) w[j] = w[j] / Z;
  int bd[KK];
#pragma unroll
  for (int j = 0; j < KK; j++) bd[j] = off[j] >> 12;  // 16-row bands
  const float* vb = vp + (size_t)b * NPIX * CVN + g * 16;
  float acc[16];
#pragma unroll
  for (int i = 0; i < 16; i++) acc[i] = 0.f;
  for (int band = 0; band < 16; band++) {
#pragma unroll
    for (int j = 0; j < KK; j++) {
      if (bd[j] == band) {
        const float4* vr = (const float4*)(vb + (size_t)off[j] * CVN);
#pragma unroll
        for (int t = 0; t < 4; t++) {
          float4 vv = vr[t];
          acc[t * 4 + 0] = acc[t * 4 + 0] + w[j] * vv.x;
          acc[t * 4 + 1] = acc[t * 4 + 1] + w[j] * vv.y;
          acc[t * 4 + 2] = acc[t * 4 + 2] + w[j] * vv.z;
          acc[t * 4 + 3] = acc[t * 4 + 3] + w[j] * vv.w;
        }
      }
    }
  }
  float* ob = out + (size_t)b * CVN * NPIX;
#pragma unroll
  for (int i = 0; i < 16; i++) ob[(size_t)(g * 16 + i) * NPIX + p] = acc[i];
}

extern "C" void kernel_launch(void* const* d_in, const int* in_sizes, int n_in,
                              void* d_out, int out_size, void* d_ws, size_t ws_size,
                              hipStream_t stream) {
  const float* q = (const float*)d_in[0];
  const float* k = (const float*)d_in[1];
  const float* v = (const float*)d_in[2];
  float* out = (float*)d_out;

  // base key: jax.random.key(42) -> (0,42); split -> enc(base,(0,i))
  uint32_t kA0, kA1, kB0, kB1;
  tf2x32(0u, 42u, 0u, 0u, kA0, kA1);
  tf2x32(0u, 42u, 0u, 1u, kB0, kB1);

  // ws layout (floats): qp2 | kp2 | cA | cB | sA | sB | vp
  const size_t szPad = (size_t)2 * CSTRT * CH;
  const size_t szCS  = (size_t)2 * KK * NPIX;
  float* qp2 = (float*)d_ws;
  float* kp2 = qp2 + szPad;
  float* cA = kp2 + szPad;
  float* cB = cA + szCS;
  int* sA = (int*)(cB + szCS);
  int* sB = sA + szCS;
  float* vp = (float*)(sB + szCS);

  hipMemsetAsync(qp2, 0, szPad * sizeof(float), stream);
  hipMemsetAsync(kp2, 0, szPad * sizeof(float), stream);
  tpad_k<<<2048, 256, 0, stream>>>(q, qp2);
  tpad_k<<<2048, 256, 0, stream>>>(k, kp2);
  vtr_k<<<2048, 256, 0, stream>>>(v, vp);

  init5_k<<<2048, 256, 0, stream>>>(qp2, kp2, cA, sA, kA0, kA1, kB0, kB1);

  float* ci = cA; int* si = sA;
  float* co = cB; int* so = sB;
  for (int it = 0; it < 5; ++it) {
    iter5_k<<<2048, 192, 0, stream>>>(qp2, kp2, ci, si, co, so, it,
                                      kA0, kA1, kB0, kB1);
    float* tc = ci; ci = co; co = tc;
    int* ts = si; si = so; so = ts;
  }
  attn5_k<<<2048, 256, 0, stream>>>(vp, ci, si, out);
}